// Round 1
// baseline (220.211 us; speedup 1.0000x reference)
//
#include <hip/hip_runtime.h>
#include <math.h>

// SelectiveSSMBlock: B=2, L=2048, D_MODEL=1024, D_STATE=16, DT_RANK=64, fp32.
// Pipeline: prep -> xz GEMM (K-split x4) -> reduce -> delta GEMM+softplus
//           -> chunked scan pass1 (S,P) -> pass2 (chunk combine -> H) -> pass3 (y).

#define LOG2E 1.44269504088896340736f

__device__ __forceinline__ float fexp2(float v){
#if defined(__has_builtin)
#if __has_builtin(__builtin_amdgcn_exp2f)
  return __builtin_amdgcn_exp2f(v);
#else
  return exp2f(v);
#endif
#else
  return exp2f(v);
#endif
}

// ---------------- prep: w2 = xpw * sigmoid(te[k]);  A2 = -exp(A_log)*log2e;  sg = sigmoid(te)
__global__ __launch_bounds__(256) void k_prep(const float* __restrict__ xpw,
                                              const float* __restrict__ alog,
                                              const float* __restrict__ te,
                                              float* __restrict__ w2,
                                              float* __restrict__ A2,
                                              float* __restrict__ sg){
  const int i = blockIdx.x * 256 + threadIdx.x;
  if (i < 98304){
    const int k = i & 1023;
    const float s = 1.f / (1.f + __expf(-te[k]));
    w2[i] = xpw[i] * s;
  }
  const int j = i - 98304;
  if (j >= 0 && j < 16384){
    A2[j] = -__expf(alog[j]) * LOG2E;
  }
  const int m = i - (98304 + 16384);
  if (m >= 0 && m < 1024){
    sg[m] = 1.f / (1.f + __expf(-te[m]));
  }
}

// ---------------- xz partial GEMM: rows 256/block (lanes=rows), 24 cols/block, K-split 4.
// Weights accessed with block-uniform addresses -> scalar loads.
__global__ __launch_bounds__(256) void k_xz(const float* __restrict__ x,
                                            const float* __restrict__ w2,
                                            float* __restrict__ xzp){
  __shared__ float xT[32][257];
  const int t = threadIdx.x;
  const int row0 = blockIdx.x * 256;   // 16 tiles
  const int c0 = blockIdx.y * 24;      // 4 col groups
  const int kbase = blockIdx.z * 256;  // 4 K-splits
  float acc[24];
#pragma unroll
  for (int c = 0; c < 24; c++) acc[c] = 0.f;
  const int kq = t & 7;      // k sub-offset (x4)
  const int rsub = t >> 3;   // 0..31
  for (int kt = 0; kt < 8; ++kt){
    const int k0 = kbase + kt * 32;
    __syncthreads();
#pragma unroll
    for (int p = 0; p < 8; p++){
      const int r = p * 32 + rsub;
      const float4 v = *reinterpret_cast<const float4*>(&x[(size_t)(row0 + r) * 1024 + k0 + kq * 4]);
      xT[kq * 4 + 0][r] = v.x; xT[kq * 4 + 1][r] = v.y;
      xT[kq * 4 + 2][r] = v.z; xT[kq * 4 + 3][r] = v.w;
    }
    __syncthreads();
#pragma unroll 4
    for (int kk = 0; kk < 32; ++kk){
      const float xv = xT[kk][t];
#pragma unroll
      for (int c = 0; c < 24; c++)
        acc[c] = fmaf(xv, w2[(size_t)(c0 + c) * 1024 + (k0 + kk)], acc[c]);
    }
  }
  float* o = xzp + ((size_t)blockIdx.z * 4096 + row0 + t) * 96 + c0;
#pragma unroll
  for (int c = 0; c < 24; c++) o[c] = acc[c];
}

// ---------------- reduce 4 K-split partials into xz (float4-wide)
__global__ __launch_bounds__(256) void k_reduce(const float4* __restrict__ p,
                                                float4* __restrict__ xz){
  const int i = blockIdx.x * 256 + threadIdx.x;  // < 98304
  const float4 a = p[i];
  const float4 b = p[i + 98304];
  const float4 c = p[i + 196608];
  const float4 d = p[i + 294912];
  float4 r;
  r.x = a.x + b.x + c.x + d.x;
  r.y = a.y + b.y + c.y + d.y;
  r.z = a.z + b.z + c.z + d.z;
  r.w = a.w + b.w + c.w + d.w;
  xz[i] = r;
}

// ---------------- delta = softplus(xz[:, :64] @ dtw^T + dtb): rows 256/block, 32 cols/block, K=64
__global__ __launch_bounds__(256) void k_delta(const float* __restrict__ xz,
                                               const float* __restrict__ dtw,
                                               const float* __restrict__ dtb,
                                               float* __restrict__ delta){
  __shared__ float dpT[32][257];
  const int t = threadIdx.x;
  const int row0 = blockIdx.x * 256;  // 16 tiles
  const int c0 = blockIdx.y * 32;     // 32 col groups
  float acc[32];
#pragma unroll
  for (int c = 0; c < 32; c++) acc[c] = 0.f;
  const int kq = t & 7;
  const int rsub = t >> 3;
  for (int kt = 0; kt < 2; ++kt){
    const int k0 = kt * 32;
    __syncthreads();
#pragma unroll
    for (int p = 0; p < 8; p++){
      const int r = p * 32 + rsub;
      const float4 v = *reinterpret_cast<const float4*>(&xz[(size_t)(row0 + r) * 96 + k0 + kq * 4]);
      dpT[kq * 4 + 0][r] = v.x; dpT[kq * 4 + 1][r] = v.y;
      dpT[kq * 4 + 2][r] = v.z; dpT[kq * 4 + 3][r] = v.w;
    }
    __syncthreads();
#pragma unroll 4
    for (int kk = 0; kk < 32; ++kk){
      const float dv = dpT[kk][t];
#pragma unroll
      for (int c = 0; c < 32; c++)
        acc[c] = fmaf(dv, dtw[(size_t)(c0 + c) * 64 + (k0 + kk)], acc[c]);
    }
  }
  float* o = delta + (size_t)(row0 + t) * 1024 + c0;
#pragma unroll
  for (int c = 0; c < 32; c++){
    const float v = acc[c] + dtb[c0 + c];
    o[c] = fmaxf(v, 0.f) + log1pf(__expf(-fabsf(v)));  // stable softplus
  }
}

// ---------------- scan pass1: per (b, d, chunk): local state S (h from 0) and decay product P
__global__ __launch_bounds__(256) void k_scan1(const float* __restrict__ delta,
                                               const float* __restrict__ x,
                                               const float* __restrict__ xz,
                                               const float* __restrict__ A2,
                                               const float* __restrict__ sg,
                                               float* __restrict__ S,
                                               float* __restrict__ P,
                                               int C, int len){
  extern __shared__ float bc[];  // len * 32 floats (B row then C row per l)
  const int t = threadIdx.x;
  const int chunk = blockIdx.x, dt4 = blockIdx.y, b = blockIdx.z;
  const int d = dt4 * 256 + t;
  const int l0 = chunk * len;
  for (int s = t; s < len * 8; s += 256){
    const int li = s >> 3, f4 = (s & 7) * 4;
    const float4 v = *reinterpret_cast<const float4*>(&xz[(size_t)(b * 2048 + l0 + li) * 96 + 64 + f4]);
    *reinterpret_cast<float4*>(&bc[li * 32 + f4]) = v;
  }
  float a2[16];
  {
    const float4* ap = reinterpret_cast<const float4*>(A2 + (size_t)d * 16);
#pragma unroll
    for (int q = 0; q < 4; q++){
      const float4 v = ap[q];
      a2[q * 4] = v.x; a2[q * 4 + 1] = v.y; a2[q * 4 + 2] = v.z; a2[q * 4 + 3] = v.w;
    }
  }
  const float sgv = sg[d];
  float h[16], Pp[16];
#pragma unroll
  for (int n = 0; n < 16; n++){ h[n] = 0.f; Pp[n] = 1.f; }
  __syncthreads();
  size_t idx = ((size_t)(b * 2048 + l0)) * 1024 + d;
  float dv = delta[idx], xv = x[idx];
  for (int li = 0; li < len; ++li){
    const size_t nidx = (li + 1 < len) ? idx + 1024 : idx;  // prefetch next l
    const float dn = delta[nidx];
    const float xn = x[nidx];
    const float du = dv * xv * sgv;
    const float* bcl = &bc[li * 32];
#pragma unroll
    for (int n = 0; n < 16; n++){
      const float tt = fexp2(dv * a2[n]);   // exp(delta*A)
      h[n] = fmaf(tt, h[n], du * bcl[n]);
      Pp[n] *= tt;
    }
    dv = dn; xv = xn; idx = nidx;
  }
  const size_t base = ((size_t)((b * C + chunk) * 1024 + d)) * 16;
#pragma unroll
  for (int q = 0; q < 4; q++){
    float4 v; v.x = h[q*4]; v.y = h[q*4+1]; v.z = h[q*4+2]; v.w = h[q*4+3];
    *reinterpret_cast<float4*>(&S[base + q * 4]) = v;
    float4 w; w.x = Pp[q*4]; w.y = Pp[q*4+1]; w.z = Pp[q*4+2]; w.w = Pp[q*4+3];
    *reinterpret_cast<float4*>(&P[base + q * 4]) = w;
  }
}

// ---------------- scan pass2: sequential chunk combine; H[c] = state entering chunk c
__global__ __launch_bounds__(256) void k_scan2(const float* __restrict__ S,
                                               const float* __restrict__ P,
                                               float* __restrict__ H, int C){
  const int g = blockIdx.x * 256 + threadIdx.x;  // < 32768 = B*D*N
  const int n = g & 15, d = (g >> 4) & 1023, b = g >> 14;
  float h = 0.f;
  for (int c = 0; c < C; c++){
    const size_t idx = ((size_t)((b * C + c) * 1024 + d)) * 16 + n;
    H[idx] = h;
    h = fmaf(P[idx], h, S[idx]);
  }
}

// ---------------- scan pass3: rerun chunk with true init, emit y = sum_n h*C + u*D
__global__ __launch_bounds__(256) void k_scan3(const float* __restrict__ delta,
                                               const float* __restrict__ x,
                                               const float* __restrict__ xz,
                                               const float* __restrict__ A2,
                                               const float* __restrict__ sg,
                                               const float* __restrict__ Dpar,
                                               const float* __restrict__ H,
                                               float* __restrict__ out,
                                               int C, int len){
  extern __shared__ float bc[];
  const int t = threadIdx.x;
  const int chunk = blockIdx.x, dt4 = blockIdx.y, b = blockIdx.z;
  const int d = dt4 * 256 + t;
  const int l0 = chunk * len;
  for (int s = t; s < len * 8; s += 256){
    const int li = s >> 3, f4 = (s & 7) * 4;
    const float4 v = *reinterpret_cast<const float4*>(&xz[(size_t)(b * 2048 + l0 + li) * 96 + 64 + f4]);
    *reinterpret_cast<float4*>(&bc[li * 32 + f4]) = v;
  }
  float a2[16];
  {
    const float4* ap = reinterpret_cast<const float4*>(A2 + (size_t)d * 16);
#pragma unroll
    for (int q = 0; q < 4; q++){
      const float4 v = ap[q];
      a2[q * 4] = v.x; a2[q * 4 + 1] = v.y; a2[q * 4 + 2] = v.z; a2[q * 4 + 3] = v.w;
    }
  }
  const float sgv = sg[d];
  const float Dv = Dpar[d];
  float h[16];
  {
    const float4* hp = reinterpret_cast<const float4*>(H + ((size_t)((b * C + chunk) * 1024 + d)) * 16);
#pragma unroll
    for (int q = 0; q < 4; q++){
      const float4 v = hp[q];
      h[q * 4] = v.x; h[q * 4 + 1] = v.y; h[q * 4 + 2] = v.z; h[q * 4 + 3] = v.w;
    }
  }
  __syncthreads();
  size_t idx = ((size_t)(b * 2048 + l0)) * 1024 + d;
  float dv = delta[idx], xv = x[idx];
  for (int li = 0; li < len; ++li){
    const size_t nidx = (li + 1 < len) ? idx + 1024 : idx;
    const float dn = delta[nidx];
    const float xn = x[nidx];
    const float du = dv * xv * sgv;
    const float* bcl = &bc[li * 32];
    float y = 0.f;
#pragma unroll
    for (int n = 0; n < 16; n++){
      const float tt = fexp2(dv * a2[n]);
      h[n] = fmaf(tt, h[n], du * bcl[n]);
      y = fmaf(h[n], bcl[16 + n], y);
    }
    out[idx] = fmaf(xv * sgv, Dv, y);
    dv = dn; xv = xn; idx = nidx;
  }
}

extern "C" void kernel_launch(void* const* d_in, const int* in_sizes, int n_in,
                              void* d_out, int out_size, void* d_ws, size_t ws_size,
                              hipStream_t stream){
  const float* x    = (const float*)d_in[0];
  const float* Alog = (const float*)d_in[1];
  const float* xpw  = (const float*)d_in[2];
  const float* dtw  = (const float*)d_in[3];
  const float* dtb  = (const float*)d_in[4];
  const float* Dpar = (const float*)d_in[5];
  const float* te   = (const float*)d_in[6];
  float* out = (float*)d_out;
  char* ws = (char*)d_ws;

  // ws layout (bytes)
  float* w2  = (float*)(ws + 0);         // 96*1024*4   = 393216
  float* A2  = (float*)(ws + 393216);    // 16384*4     = 65536
  float* sg  = (float*)(ws + 458752);    // 1024*4      = 4096
  float* xz  = (float*)(ws + 462848);    // 4096*96*4   = 1572864
  float* del = (float*)(ws + 2035712);   // 4096*1024*4 = 16777216
  char*  r1  = ws + 18812928;            // xz partials (6291456) alias S/P/H (disjoint lifetime)
  float* xzp = (float*)r1;

  // chunk count: prefer 64 (best occupancy), degrade if ws is small
  int C;
  if      (ws_size >= 18812928ull + 3ull * 131072ull * 64ull) C = 64;
  else if (ws_size >= 18812928ull + 3ull * 131072ull * 32ull) C = 32;
  else                                                        C = 16;
  const int len = 2048 / C;
  const size_t SZ = (size_t)131072 * C;  // bytes per S/P/H array
  float* S  = (float*)r1;
  float* P  = (float*)(r1 + SZ);
  float* Hh = (float*)(r1 + 2 * SZ);

  hipLaunchKernelGGL(k_prep,   dim3(452),      dim3(256), 0, stream, xpw, Alog, te, w2, A2, sg);
  hipLaunchKernelGGL(k_xz,     dim3(16, 4, 4), dim3(256), 0, stream, x, w2, xzp);
  hipLaunchKernelGGL(k_reduce, dim3(384),      dim3(256), 0, stream, (const float4*)xzp, (float4*)xz);
  hipLaunchKernelGGL(k_delta,  dim3(16, 32),   dim3(256), 0, stream, xz, dtw, dtb, del);
  hipLaunchKernelGGL(k_scan1,  dim3(C, 4, 2),  dim3(256), len * 128, stream, del, x, xz, A2, sg, S, P, C, len);
  hipLaunchKernelGGL(k_scan2,  dim3(128),      dim3(256), 0, stream, S, P, Hh, C);
  hipLaunchKernelGGL(k_scan3,  dim3(C, 4, 2),  dim3(256), len * 128, stream, del, x, xz, A2, sg, Dpar, Hh, out, C, len);
}

// Round 2
// 194.422 us; speedup vs baseline: 1.1326x; 1.1326x over previous
//
#include <hip/hip_runtime.h>
#include <math.h>

// SelectiveSSMBlock: B=2, L=2048, D_MODEL=1024, D_STATE=16, DT_RANK=64, fp32.
// R2: transposed weight layouts (contiguous block-uniform scalar loads) +
//     bigger K-split grid for occupancy on the two GEMMs.

#define LOG2E 1.44269504088896340736f

__device__ __forceinline__ float fexp2(float v){
#if defined(__has_builtin)
#if __has_builtin(__builtin_amdgcn_exp2f)
  return __builtin_amdgcn_exp2f(v);
#else
  return exp2f(v);
#endif
#else
  return exp2f(v);
#endif
}

// ---------------- prep: w2T[k][96] = xpw[c][k]*sigmoid(te[k]);  dtwT[kk][d] = dtw[d][kk];
//                  A2 = -exp(A_log)*log2e;  sg = sigmoid(te)
__global__ __launch_bounds__(256) void k_prep(const float* __restrict__ xpw,
                                              const float* __restrict__ dtw,
                                              const float* __restrict__ alog,
                                              const float* __restrict__ te,
                                              float* __restrict__ w2T,
                                              float* __restrict__ dtwT,
                                              float* __restrict__ A2,
                                              float* __restrict__ sg){
  const int b = blockIdx.x, t = threadIdx.x;
  if (b < 1024){
    if (t < 96){
      const float s = 1.f / (1.f + __expf(-te[b]));
      w2T[b * 96 + t] = xpw[(size_t)t * 1024 + b] * s;
    }
  } else if (b < 1088){
    const int kk = b - 1024;
#pragma unroll
    for (int i = 0; i < 4; i++){
      const int d = i * 256 + t;
      dtwT[kk * 1024 + d] = dtw[(size_t)d * 64 + kk];
    }
  } else if (b < 1152){
    const int j = (b - 1088) * 256 + t;
    A2[j] = -__expf(alog[j]) * LOG2E;
  } else {
    const int m = (b - 1152) * 256 + t;
    if (m < 1024) sg[m] = 1.f / (1.f + __expf(-te[m]));
  }
}

// ---------------- xz partial GEMM: 256 rows/block (lane=row), 32 cols/block, K-split S.
// Weights: w2T[k][96] -> per-kk 32 contiguous floats, block-uniform -> s_load_dwordx16.
__global__ __launch_bounds__(256) void k_xz(const float* __restrict__ x,
                                            const float* __restrict__ w2T,
                                            float* __restrict__ xzp,
                                            int KC){
  __shared__ float xT[32][257];
  const int t = threadIdx.x;
  const int row0 = blockIdx.x * 256;   // 16 tiles
  const int c0 = blockIdx.y * 32;      // 3 col groups
  const int kbase = blockIdx.z * KC;   // K-splits
  float acc[32];
#pragma unroll
  for (int c = 0; c < 32; c++) acc[c] = 0.f;
  const int kq = t & 7;      // k sub-offset (x4)
  const int rsub = t >> 3;   // 0..31
  const int nkt = KC >> 5;
  for (int kt = 0; kt < nkt; ++kt){
    const int k0 = kbase + kt * 32;
    __syncthreads();
#pragma unroll
    for (int p = 0; p < 8; p++){
      const int r = p * 32 + rsub;
      const float4 v = *reinterpret_cast<const float4*>(&x[(size_t)(row0 + r) * 1024 + k0 + kq * 4]);
      xT[kq * 4 + 0][r] = v.x; xT[kq * 4 + 1][r] = v.y;
      xT[kq * 4 + 2][r] = v.z; xT[kq * 4 + 3][r] = v.w;
    }
    __syncthreads();
#pragma unroll 4
    for (int kk = 0; kk < 32; ++kk){
      const float xv = xT[kk][t];
      const float* wr = &w2T[(size_t)(k0 + kk) * 96 + c0];
#pragma unroll
      for (int c = 0; c < 32; c++)
        acc[c] = fmaf(xv, wr[c], acc[c]);
    }
  }
  float* o = xzp + ((size_t)blockIdx.z * 4096 + row0 + t) * 96 + c0;
#pragma unroll
  for (int c = 0; c < 32; c++) o[c] = acc[c];
}

// ---------------- reduce S K-split partials into xz (float4-wide)
__global__ __launch_bounds__(256) void k_reduce(const float4* __restrict__ p,
                                                float4* __restrict__ xz, int S){
  const int i = blockIdx.x * 256 + threadIdx.x;  // < 98304
  float4 r = p[i];
#pragma unroll 4
  for (int s = 1; s < S; s++){
    const float4 a = p[(size_t)s * 98304 + i];
    r.x += a.x; r.y += a.y; r.z += a.z; r.w += a.w;
  }
  xz[i] = r;
}

// ---------------- delta = softplus(xz[:, :64] @ dtw^T + dtb): 256 rows/block, 32 cols/block, K=64
// Weights: dtwT[kk][d] -> per-kk 32 contiguous floats, block-uniform.
__global__ __launch_bounds__(256) void k_delta(const float* __restrict__ xz,
                                               const float* __restrict__ dtwT,
                                               const float* __restrict__ dtb,
                                               float* __restrict__ delta){
  __shared__ float dpT[32][257];
  const int t = threadIdx.x;
  const int row0 = blockIdx.x * 256;  // 16 tiles
  const int c0 = blockIdx.y * 32;     // 32 col groups
  float acc[32];
#pragma unroll
  for (int c = 0; c < 32; c++) acc[c] = 0.f;
  const int kq = t & 7;
  const int rsub = t >> 3;
  for (int kt = 0; kt < 2; ++kt){
    const int k0 = kt * 32;
    __syncthreads();
#pragma unroll
    for (int p = 0; p < 8; p++){
      const int r = p * 32 + rsub;
      const float4 v = *reinterpret_cast<const float4*>(&xz[(size_t)(row0 + r) * 96 + k0 + kq * 4]);
      dpT[kq * 4 + 0][r] = v.x; dpT[kq * 4 + 1][r] = v.y;
      dpT[kq * 4 + 2][r] = v.z; dpT[kq * 4 + 3][r] = v.w;
    }
    __syncthreads();
#pragma unroll 4
    for (int kk = 0; kk < 32; ++kk){
      const float dv = dpT[kk][t];
      const float* wr = &dtwT[(size_t)(k0 + kk) * 1024 + c0];
#pragma unroll
      for (int c = 0; c < 32; c++)
        acc[c] = fmaf(dv, wr[c], acc[c]);
    }
  }
  float* o = delta + (size_t)(row0 + t) * 1024 + c0;
#pragma unroll
  for (int c = 0; c < 32; c++){
    const float v = acc[c] + dtb[c0 + c];
    o[c] = fmaxf(v, 0.f) + log1pf(__expf(-fabsf(v)));  // stable softplus
  }
}

// ---------------- scan pass1: per (b, d, chunk): local state S (h from 0) and decay product P
__global__ __launch_bounds__(256) void k_scan1(const float* __restrict__ delta,
                                               const float* __restrict__ x,
                                               const float* __restrict__ xz,
                                               const float* __restrict__ A2,
                                               const float* __restrict__ sg,
                                               float* __restrict__ S,
                                               float* __restrict__ P,
                                               int C, int len){
  extern __shared__ float bc[];  // len * 32 floats (B row then C row per l)
  const int t = threadIdx.x;
  const int chunk = blockIdx.x, dt4 = blockIdx.y, b = blockIdx.z;
  const int d = dt4 * 256 + t;
  const int l0 = chunk * len;
  for (int s = t; s < len * 8; s += 256){
    const int li = s >> 3, f4 = (s & 7) * 4;
    const float4 v = *reinterpret_cast<const float4*>(&xz[(size_t)(b * 2048 + l0 + li) * 96 + 64 + f4]);
    *reinterpret_cast<float4*>(&bc[li * 32 + f4]) = v;
  }
  float a2[16];
  {
    const float4* ap = reinterpret_cast<const float4*>(A2 + (size_t)d * 16);
#pragma unroll
    for (int q = 0; q < 4; q++){
      const float4 v = ap[q];
      a2[q * 4] = v.x; a2[q * 4 + 1] = v.y; a2[q * 4 + 2] = v.z; a2[q * 4 + 3] = v.w;
    }
  }
  const float sgv = sg[d];
  float h[16], Pp[16];
#pragma unroll
  for (int n = 0; n < 16; n++){ h[n] = 0.f; Pp[n] = 1.f; }
  __syncthreads();
  size_t idx = ((size_t)(b * 2048 + l0)) * 1024 + d;
  float dv = delta[idx], xv = x[idx];
  for (int li = 0; li < len; ++li){
    const size_t nidx = (li + 1 < len) ? idx + 1024 : idx;  // prefetch next l
    const float dn = delta[nidx];
    const float xn = x[nidx];
    const float du = dv * xv * sgv;
    const float* bcl = &bc[li * 32];
#pragma unroll
    for (int n = 0; n < 16; n++){
      const float tt = fexp2(dv * a2[n]);   // exp(delta*A)
      h[n] = fmaf(tt, h[n], du * bcl[n]);
      Pp[n] *= tt;
    }
    dv = dn; xv = xn; idx = nidx;
  }
  const size_t base = ((size_t)((b * C + chunk) * 1024 + d)) * 16;
#pragma unroll
  for (int q = 0; q < 4; q++){
    float4 v; v.x = h[q*4]; v.y = h[q*4+1]; v.z = h[q*4+2]; v.w = h[q*4+3];
    *reinterpret_cast<float4*>(&S[base + q * 4]) = v;
    float4 w; w.x = Pp[q*4]; w.y = Pp[q*4+1]; w.z = Pp[q*4+2]; w.w = Pp[q*4+3];
    *reinterpret_cast<float4*>(&P[base + q * 4]) = w;
  }
}

// ---------------- scan pass2: sequential chunk combine; H[c] = state entering chunk c
__global__ __launch_bounds__(256) void k_scan2(const float* __restrict__ S,
                                               const float* __restrict__ P,
                                               float* __restrict__ H, int C){
  const int g = blockIdx.x * 256 + threadIdx.x;  // < 32768 = B*D*N
  const int n = g & 15, d = (g >> 4) & 1023, b = g >> 14;
  float h = 0.f;
  for (int c = 0; c < C; c++){
    const size_t idx = ((size_t)((b * C + c) * 1024 + d)) * 16 + n;
    H[idx] = h;
    h = fmaf(P[idx], h, S[idx]);
  }
}

// ---------------- scan pass3: rerun chunk with true init, emit y = sum_n h*C + u*D
__global__ __launch_bounds__(256) void k_scan3(const float* __restrict__ delta,
                                               const float* __restrict__ x,
                                               const float* __restrict__ xz,
                                               const float* __restrict__ A2,
                                               const float* __restrict__ sg,
                                               const float* __restrict__ Dpar,
                                               const float* __restrict__ H,
                                               float* __restrict__ out,
                                               int C, int len){
  extern __shared__ float bc[];
  const int t = threadIdx.x;
  const int chunk = blockIdx.x, dt4 = blockIdx.y, b = blockIdx.z;
  const int d = dt4 * 256 + t;
  const int l0 = chunk * len;
  for (int s = t; s < len * 8; s += 256){
    const int li = s >> 3, f4 = (s & 7) * 4;
    const float4 v = *reinterpret_cast<const float4*>(&xz[(size_t)(b * 2048 + l0 + li) * 96 + 64 + f4]);
    *reinterpret_cast<float4*>(&bc[li * 32 + f4]) = v;
  }
  float a2[16];
  {
    const float4* ap = reinterpret_cast<const float4*>(A2 + (size_t)d * 16);
#pragma unroll
    for (int q = 0; q < 4; q++){
      const float4 v = ap[q];
      a2[q * 4] = v.x; a2[q * 4 + 1] = v.y; a2[q * 4 + 2] = v.z; a2[q * 4 + 3] = v.w;
    }
  }
  const float sgv = sg[d];
  const float Dv = Dpar[d];
  float h[16];
  {
    const float4* hp = reinterpret_cast<const float4*>(H + ((size_t)((b * C + chunk) * 1024 + d)) * 16);
#pragma unroll
    for (int q = 0; q < 4; q++){
      const float4 v = hp[q];
      h[q * 4] = v.x; h[q * 4 + 1] = v.y; h[q * 4 + 2] = v.z; h[q * 4 + 3] = v.w;
    }
  }
  __syncthreads();
  size_t idx = ((size_t)(b * 2048 + l0)) * 1024 + d;
  float dv = delta[idx], xv = x[idx];
  for (int li = 0; li < len; ++li){
    const size_t nidx = (li + 1 < len) ? idx + 1024 : idx;
    const float dn = delta[nidx];
    const float xn = x[nidx];
    const float du = dv * xv * sgv;
    const float* bcl = &bc[li * 32];
    float y = 0.f;
#pragma unroll
    for (int n = 0; n < 16; n++){
      const float tt = fexp2(dv * a2[n]);
      h[n] = fmaf(tt, h[n], du * bcl[n]);
      y = fmaf(h[n], bcl[16 + n], y);
    }
    out[idx] = fmaf(xv * sgv, Dv, y);
    dv = dn; xv = xn; idx = nidx;
  }
}

extern "C" void kernel_launch(void* const* d_in, const int* in_sizes, int n_in,
                              void* d_out, int out_size, void* d_ws, size_t ws_size,
                              hipStream_t stream){
  const float* x    = (const float*)d_in[0];
  const float* Alog = (const float*)d_in[1];
  const float* xpw  = (const float*)d_in[2];
  const float* dtw  = (const float*)d_in[3];
  const float* dtb  = (const float*)d_in[4];
  const float* Dpar = (const float*)d_in[5];
  const float* te   = (const float*)d_in[6];
  float* out = (float*)d_out;
  char* ws = (char*)d_ws;

  // ws layout (bytes)
  float* w2T  = (float*)(ws + 0);         // 1024*96*4   = 393216
  float* A2   = (float*)(ws + 393216);    // 16384*4     = 65536
  float* sg   = (float*)(ws + 458752);    // 1024*4      = 4096
  float* dtwT = (float*)(ws + 462848);    // 64*1024*4   = 262144
  float* xz   = (float*)(ws + 724992);    // 4096*96*4   = 1572864
  float* del  = (float*)(ws + 2297856);   // 4096*1024*4 = 16777216
  char*  r1   = ws + 19075072;            // xz partials alias S/P/H (disjoint lifetime)
  float* xzp  = (float*)r1;

  // chunk count C (scan parallelism) and K-split S (xz GEMM), sized to ws
  int C, Ksp;
  if      (ws_size >= 19075072ull + 3ull * 131072ull * 64ull) { C = 64; Ksp = 16; }
  else if (ws_size >= 19075072ull + 3ull * 131072ull * 32ull) { C = 32; Ksp = 8;  }
  else                                                        { C = 16; Ksp = 4;  }
  const int len = 2048 / C;
  const int KC = 1024 / Ksp;
  const size_t SZ = (size_t)131072 * C;  // bytes per S/P/H array
  float* S  = (float*)r1;
  float* P  = (float*)(r1 + SZ);
  float* Hh = (float*)(r1 + 2 * SZ);

  hipLaunchKernelGGL(k_prep,   dim3(1156),       dim3(256), 0, stream, xpw, dtw, Alog, te, w2T, dtwT, A2, sg);
  hipLaunchKernelGGL(k_xz,     dim3(16, 3, Ksp), dim3(256), 0, stream, x, w2T, xzp, KC);
  hipLaunchKernelGGL(k_reduce, dim3(384),        dim3(256), 0, stream, (const float4*)xzp, (float4*)xz, Ksp);
  hipLaunchKernelGGL(k_delta,  dim3(16, 32),     dim3(256), 0, stream, xz, dtwT, dtb, del);
  hipLaunchKernelGGL(k_scan1,  dim3(C, 4, 2),    dim3(256), len * 128, stream, del, x, xz, A2, sg, S, P, C, len);
  hipLaunchKernelGGL(k_scan2,  dim3(128),        dim3(256), 0, stream, S, P, Hh, C);
  hipLaunchKernelGGL(k_scan3,  dim3(C, 4, 2),    dim3(256), len * 128, stream, del, x, xz, A2, sg, Dpar, Hh, out, C, len);
}